// Round 1
// baseline (375.530 us; speedup 1.0000x reference)
//
#include <hip/hip_runtime.h>
#include <stdint.h>

// LinearDiscriminator: [T,B,H] fp32 -> MLP(1024->100->10->1) -> logsigmoid
// -> masked sum over T -> exp -> [B] fp32.
// T=2048 B=32 H=1024. Layer1/2 via bf16 MFMA (fp32 acc), layer3+logsig fp32.
// HBM-bound: predicated A-loads skip rows with t >= lengths[b] (~2x traffic cut).

#define T_DIM 2048
#define B_DIM 32
#define H_DIM 1024
#define L1_DIM 100
#define L1_PAD 112   // 7 * 16
#define L2_DIM 10
#define L2_PAD 16
#define K2_PAD 128   // layer-2 K padded (100 -> 128)
#define NBLK  1024   // T*B/64 row-tiles

#define W1B_ELEMS (L1_PAD * H_DIM)   // 114688 bf16
#define W2B_ELEMS (L2_PAD * K2_PAD)  // 2048 bf16
#define PART_OFF_BYTES ((W1B_ELEMS + W2B_ELEMS) * 2)  // partials: fp32 [32][NBLK]

typedef float v4f __attribute__((ext_vector_type(4)));
typedef short s8  __attribute__((ext_vector_type(8)));

static __device__ __forceinline__ unsigned short f2bf(float f) {
    // round-to-nearest-even f32 -> bf16 (inputs finite; no NaN handling needed)
    unsigned int u = __float_as_uint(f);
    u += 0x7fffu + ((u >> 16) & 1u);
    return (unsigned short)(u >> 16);
}

// ---------------- kernel 0: weight convert + pad ----------------
__global__ void convert_weights(const float* __restrict__ W1,
                                const float* __restrict__ W2,
                                unsigned short* __restrict__ wsb) {
    int i = blockIdx.x * 256 + threadIdx.x;
    if (i < W1B_ELEMS) {
        int row = i >> 10, col = i & 1023;
        float v = (row < L1_DIM) ? W1[row * H_DIM + col] : 0.0f;
        wsb[i] = f2bf(v);
    } else {
        int j = i - W1B_ELEMS;
        if (j < W2B_ELEMS) {
            int r = j >> 7, c = j & 127;
            float v = (r < L2_DIM && c < L1_DIM) ? W2[r * L1_DIM + c] : 0.0f;
            wsb[W1B_ELEMS + j] = f2bf(v);
        }
    }
}

// ---------------- kernel 1: main fused MLP ----------------
__global__ __launch_bounds__(256) void mlp_main(
    const float* __restrict__ enc,      // [T][B][H] fp32
    const int*   __restrict__ lenp,     // int32, or int64 (runtime-detected)
    const float* __restrict__ b1,
    const float* __restrict__ b2,
    const float* __restrict__ W3,
    const float* __restrict__ b3,
    const unsigned short* __restrict__ w1b,  // bf16 [112][1024]
    const unsigned short* __restrict__ w2b,  // bf16 [16][128]
    float* __restrict__ partials)            // fp32 [32][NBLK]
{
    __shared__ __align__(16) unsigned short ldsB[L1_PAD][72];  // W1 chunk BK=64 (+8 pad)
    __shared__ __align__(16) unsigned short ldsH[64][136];     // h1 bf16, K2_PAD cols (+8 pad)
    __shared__ __align__(16) unsigned short ldsW2[L2_PAD][136];
    __shared__ float ldsPart[2][32];

    const int tid  = threadIdx.x;
    const int blk  = blockIdx.x;
    const int lane = tid & 63;
    const int w    = tid >> 6;    // wave 0..3
    const int m    = lane & 15;
    const int q    = lane >> 4;

    // lengths: detect int64 (lengths >= 1, so low word of elem0's high half == 0 iff int64)
    const bool is64 = (lenp[1] == 0);

    // block covers rows [blk*64, blk*64+64) = t in {2blk, 2blk+1}, all 32 b.
    const int tA = 2 * blk + (w >> 1);
    const int bA = ((w & 1) << 4) + m;             // A-layout row's b (row = m)
    const int lenA = is64 ? lenp[2 * bA] : lenp[bA];
    const bool predA = (tA < lenA);

    // early exit if every row masked
    int maxlen = 0;
    for (int i = 0; i < B_DIM; ++i) {
        int L = is64 ? lenp[2 * i] : lenp[i];
        maxlen = max(maxlen, L);
    }
    if (2 * blk >= maxlen) {
        if (tid < 32) partials[tid * NBLK + blk] = 0.0f;
        return;
    }

    // stage W2 bf16 [16][128] -> ldsW2 (16B per thread)
    {
        int r = tid >> 4;
        int c = (tid & 15) << 3;
        *(uint4*)&ldsW2[r][c] = *(const uint4*)(w2b + r * K2_PAD + c);
    }

    // per-lane constants
    float b1v[7];
#pragma unroll
    for (int nt = 0; nt < 7; ++nt) {
        int n = nt * 16 + m;
        b1v[nt] = (n < L1_DIM) ? b1[n] : 0.0f;
    }
    const float b2v = (m < L2_DIM) ? b2[m] : 0.0f;
    const float w3v = (m < L2_DIM) ? W3[m] : 0.0f;
    const float b3s = b3[0];

    // A pointer: global row blk*64 + w*16 + m, col base q*8
    const float* aptr = enc + (size_t)(blk * 64 + w * 16 + m) * H_DIM + q * 8;

    v4f acc[7];
#pragma unroll
    for (int nt = 0; nt < 7; ++nt) acc[nt] = (v4f)0.0f;

    // ---- layer-1 K loop: 16 chunks of BK=64 ----
    for (int kc = 0; kc < 16; ++kc) {
        __syncthreads();
        // stage W1 chunk [112][64] bf16 from L2 (896 x 16B units, 256 threads)
        {
            int base = tid;
#pragma unroll
            for (int it = 0; it < 4; ++it, base += 256) {
                if (it < 3 || base < 896) {
                    int r = base >> 3;
                    int c = (base & 7) << 3;
                    *(uint4*)&ldsB[r][c] =
                        *(const uint4*)(w1b + r * H_DIM + kc * 64 + c);
                }
            }
        }
        __syncthreads();
#pragma unroll
        for (int ks = 0; ks < 2; ++ks) {
            const int k0 = kc * 64 + ks * 32;
            float4 x0, x1;
            if (predA) {
                x0 = *(const float4*)(aptr + k0);
                x1 = *(const float4*)(aptr + k0 + 4);
            } else {
                x0 = make_float4(0.f, 0.f, 0.f, 0.f);
                x1 = make_float4(0.f, 0.f, 0.f, 0.f);
            }
            s8 afrag;
            afrag[0] = (short)f2bf(x0.x); afrag[1] = (short)f2bf(x0.y);
            afrag[2] = (short)f2bf(x0.z); afrag[3] = (short)f2bf(x0.w);
            afrag[4] = (short)f2bf(x1.x); afrag[5] = (short)f2bf(x1.y);
            afrag[6] = (short)f2bf(x1.z); afrag[7] = (short)f2bf(x1.w);
#pragma unroll
            for (int nt = 0; nt < 7; ++nt) {
                s8 bfrag = *(const s8*)&ldsB[nt * 16 + m][ks * 32 + q * 8];
                acc[nt] = __builtin_amdgcn_mfma_f32_16x16x32_bf16(
                    afrag, bfrag, acc[nt], 0, 0, 0);
            }
        }
    }

    __syncthreads();
    // ---- h1 = relu(acc + b1) -> LDS bf16 (C-layout: row=q*4+reg, col=nt*16+m) ----
#pragma unroll
    for (int nt = 0; nt < 7; ++nt) {
#pragma unroll
        for (int reg = 0; reg < 4; ++reg) {
            float h = fmaxf(acc[nt][reg] + b1v[nt], 0.0f);
            ldsH[w * 16 + q * 4 + reg][nt * 16 + m] = f2bf(h);
        }
    }
    // zero K-pad cols 112..127 (avoid uninit-LDS NaN * 0 in stage-2 MFMA)
    {
        int r = tid >> 2;
        int c = 112 + ((tid & 3) << 2);
        *(uint2*)&ldsH[r][c] = make_uint2(0u, 0u);
    }
    __syncthreads();

    // ---- layer-2 MFMA: [64 rows] x [16 cols] over K=128 ----
    v4f acc2 = (v4f)0.0f;
#pragma unroll
    for (int ks = 0; ks < 4; ++ks) {
        s8 a2  = *(const s8*)&ldsH[w * 16 + m][ks * 32 + q * 8];
        s8 b2f = *(const s8*)&ldsW2[m][ks * 32 + q * 8];
        acc2 = __builtin_amdgcn_mfma_f32_16x16x32_bf16(a2, b2f, acc2, 0, 0, 0);
    }

    // ---- layer 3 + logsigmoid ----
    v4f z;
#pragma unroll
    for (int reg = 0; reg < 4; ++reg) {
        float y2 = fmaxf(acc2[reg] + b2v, 0.0f);   // col j = m
        z[reg] = y2 * w3v;
    }
    // reduce over j across the 16-lane group (lanes share rows q*4+reg)
#pragma unroll
    for (int msk = 1; msk < 16; msk <<= 1) {
#pragma unroll
        for (int reg = 0; reg < 4; ++reg)
            z[reg] += __shfl_xor(z[reg], msk, 16);
    }
    if (m == 0) {
#pragma unroll
        for (int reg = 0; reg < 4; ++reg) {
            int rowLocal = q * 4 + reg;                   // row in wave tile
            int bC = ((w & 1) << 4) + rowLocal;           // its b
            int lenC = is64 ? lenp[2 * bC] : lenp[bC];
            float logit = z[reg] + b3s;
            float logp  = fminf(logit, 0.0f) - log1pf(__expf(-fabsf(logit)));
            ldsPart[w >> 1][bC] = (tA < lenC) ? logp : 0.0f;
        }
    }
    __syncthreads();
    if (tid < 32)
        partials[tid * NBLK + blk] = ldsPart[0][tid] + ldsPart[1][tid];
}

// ---------------- kernel 2: reduce + exp ----------------
__global__ void finalize(const float* __restrict__ partials,
                         float* __restrict__ out) {
    const int b = blockIdx.x;
    const int tid = threadIdx.x;
    float s = 0.0f;
    for (int i = tid; i < NBLK; i += 256) s += partials[b * NBLK + i];
#pragma unroll
    for (int off = 32; off > 0; off >>= 1) s += __shfl_down(s, off, 64);
    __shared__ float red[4];
    if ((tid & 63) == 0) red[tid >> 6] = s;
    __syncthreads();
    if (tid == 0) out[b] = expf(red[0] + red[1] + red[2] + red[3]);
}

extern "C" void kernel_launch(void* const* d_in, const int* in_sizes, int n_in,
                              void* d_out, int out_size, void* d_ws, size_t ws_size,
                              hipStream_t stream) {
    const float* enc = (const float*)d_in[0];
    const int*   len = (const int*)d_in[1];
    const float* W1  = (const float*)d_in[2];
    const float* b1  = (const float*)d_in[3];
    const float* W2  = (const float*)d_in[4];
    const float* b2  = (const float*)d_in[5];
    const float* W3  = (const float*)d_in[6];
    const float* b3  = (const float*)d_in[7];

    unsigned short* wsb = (unsigned short*)d_ws;
    float* partials = (float*)((char*)d_ws + PART_OFF_BYTES);
    float* out = (float*)d_out;

    convert_weights<<<(W1B_ELEMS + W2B_ELEMS + 255) / 256, 256, 0, stream>>>(W1, W2, wsb);
    mlp_main<<<NBLK, 256, 0, stream>>>(enc, len, b1, b2, W3, b3,
                                       wsb, wsb + W1B_ELEMS, partials);
    finalize<<<B_DIM, 256, 0, stream>>>(partials, out);
}